// Round 2
// baseline (351.844 us; speedup 1.0000x reference)
//
#include <hip/hip_runtime.h>

// Segment-sum via counting-sort CSR + gather-reduce.
// R9 (resubmit; prior two rounds hit GPU-acquisition timeouts, never measured):
// reduce_kernel hoists the per-row `ids` reads into ONE coalesced 4B/lane
// load (ids are contiguous per row), then distributes edge indices via
// wave-uniform __shfl. Removes the serial ids-load from the gather
// dependent chain (theory: reduce is latency-bound, avg deg 16 -> only
// 1-2 iterations/wave to hide ~2 full HBM latencies).
// Pipeline (hist/scan/scatter) unchanged from R8 for clean attribution.

#define TILE 1024  // scan tile: 256 threads x 4 elems

__global__ __launch_bounds__(256) void hist_rank_kernel(
    const int* __restrict__ edge0, int* __restrict__ counts,
    int* __restrict__ rank, int E)
{
    int t = blockIdx.x * blockDim.x + threadIdx.x;
    int base = t * 4;
    if (base + 3 < E) {
        int4 r = ((const int4*)edge0)[t];
        int4 k;
        k.x = atomicAdd(&counts[r.x], 1);
        k.y = atomicAdd(&counts[r.y], 1);
        k.z = atomicAdd(&counts[r.z], 1);
        k.w = atomicAdd(&counts[r.w], 1);
        ((int4*)rank)[t] = k;
    } else {
        for (int i = base; i < E; ++i) rank[i] = atomicAdd(&counts[edge0[i]], 1);
    }
}

__global__ __launch_bounds__(256) void scan_partial(
    const int* __restrict__ counts, int* __restrict__ tileSum, int N)
{
    __shared__ int wsum[4];
    int t = threadIdx.x;
    int base = blockIdx.x * TILE + t * 4;
    int s = 0;
    #pragma unroll
    for (int k = 0; k < 4; ++k) {
        int i = base + k;
        if (i < N) s += counts[i];
    }
    for (int off = 1; off < 64; off <<= 1) s += __shfl_xor(s, off);
    if ((t & 63) == 0) wsum[t >> 6] = s;
    __syncthreads();
    if (t == 0) tileSum[blockIdx.x] = wsum[0] + wsum[1] + wsum[2] + wsum[3];
}

// Each block redundantly scans the (<=64) tile sums in its first wave to get
// its own tile prefix, then writes its tile's exclusive offsets.
// numTiles must be <= 64 (N <= 65536; here N = 50000 -> 49 tiles).
__global__ __launch_bounds__(256) void scan_final(
    const int* __restrict__ counts, const int* __restrict__ tileSum,
    int* __restrict__ offsets, int N, int E, int numTiles)
{
    __shared__ int wtot[4];
    __shared__ int tilePre;
    int t = threadIdx.x;
    int lane = t & 63, wv = t >> 6;

    if (t < 64) {                            // wave 0: scan tile sums
        int v0 = (t < numTiles) ? tileSum[t] : 0;
        int v = v0;
        #pragma unroll
        for (int off = 1; off < 64; off <<= 1) {
            int u = __shfl_up(v, off);
            if (t >= off) v += u;
        }
        if (t == blockIdx.x) tilePre = v - v0;   // exclusive prefix of this tile
    }
    if (blockIdx.x == 0 && t == 0) offsets[N] = E;

    int base = blockIdx.x * TILE + t * 4;
    int c[4]; int s = 0;
    #pragma unroll
    for (int k = 0; k < 4; ++k) {
        int i = base + k;
        c[k] = (i < N) ? counts[i] : 0;
        s += c[k];
    }
    int inc = s;
    #pragma unroll
    for (int off = 1; off < 64; off <<= 1) {
        int u = __shfl_up(inc, off);
        if (lane >= off) inc += u;
    }
    if (lane == 63) wtot[wv] = inc;
    __syncthreads();
    int wpre = 0;
    for (int w = 0; w < wv; ++w) wpre += wtot[w];
    int pre = tilePre + wpre + (inc - s);
    #pragma unroll
    for (int k = 0; k < 4; ++k) {
        int i = base + k;
        if (i < N) offsets[i] = pre;
        pre += c[k];
    }
}

// Deterministic scatter: pure loads + stores, no atomics.
__global__ __launch_bounds__(256) void scatter_kernel(
    const int* __restrict__ edge0, const int* __restrict__ rank,
    const int* __restrict__ offsets, int* __restrict__ ids, int E)
{
    int t = blockIdx.x * blockDim.x + threadIdx.x;
    int base = t * 4;
    if (base + 3 < E) {
        int4 r = ((const int4*)edge0)[t];
        int4 k = ((const int4*)rank)[t];
        ids[offsets[r.x] + k.x] = base;
        ids[offsets[r.y] + k.y] = base + 1;
        ids[offsets[r.z] + k.z] = base + 2;
        ids[offsets[r.w] + k.w] = base + 3;
    } else {
        for (int i = base; i < E; ++i) ids[offsets[edge0[i]] + rank[i]] = i;
    }
}

// 1 wave per row. lane = 8*sub + g: 8 edge-slots (sub), lane covers features
// [8g, 8g+8) as 2 float4.
// R9: row's ids (contiguous) preloaded with ONE coalesced load into a VGPR
// (ids[beg+lane]); inner loop gets edge indices via wave-uniform __shfl, so
// the w4 gathers have no serial global-load ahead of them. Fallback to
// memory loads for the (rare) deg>64 remainder.
__global__ __launch_bounds__(256) void reduce_kernel(
    const int* __restrict__ offsets, const int* __restrict__ ids,
    const float4* __restrict__ w4, float4* __restrict__ out4, int N)
{
    int row = blockIdx.x * 4 + (threadIdx.x >> 6);
    if (row >= N) return;
    int lane = threadIdx.x & 63;
    int sub = lane >> 3, g = lane & 7;       // sub: edge-slot, g: feature-octet
    int beg = offsets[row], end = offsets[row + 1];
    int deg = end - beg;

    float4 a0 = make_float4(0.f, 0.f, 0.f, 0.f);
    float4 a1 = make_float4(0.f, 0.f, 0.f, 0.f);

    // One coalesced load: lane i holds ids[beg+i] (valid for i < deg).
    int nloc = deg < 64 ? deg : 64;
    int myid = (lane < deg) ? ids[beg + lane] : 0;

    const float4* __restrict__ wp = w4 + g * 2;

    // Main loop over full 16-edge groups: all shuffles wave-uniform, all
    // lanes valid -> 4 independent float4 gathers in flight per iteration.
    int full = nloc & ~15;
    for (int b = 0; b < full; b += 16) {
        int e0 = __shfl(myid, b + sub);
        int e1 = __shfl(myid, b + 8 + sub);
        float4 w00 = wp[(size_t)e0 * 16];
        float4 w01 = wp[(size_t)e0 * 16 + 1];
        float4 w10 = wp[(size_t)e1 * 16];
        float4 w11 = wp[(size_t)e1 * 16 + 1];
        a0.x += w00.x + w10.x; a0.y += w00.y + w10.y;
        a0.z += w00.z + w10.z; a0.w += w00.w + w10.w;
        a1.x += w01.x + w11.x; a1.y += w01.y + w11.y;
        a1.z += w01.z + w11.z; a1.w += w01.w + w11.w;
    }
    // Remainder (1..15 local edges): shuffles still executed by all lanes
    // (wave-uniform), loads predicated.
    if (full < nloc) {
        int s0 = full + sub;
        int s1 = full + 8 + sub;
        int e0 = __shfl(myid, s0 & 63);
        int e1 = __shfl(myid, s1 & 63);
        if (s0 < nloc) {
            float4 w0 = wp[(size_t)e0 * 16];
            float4 w1 = wp[(size_t)e0 * 16 + 1];
            a0.x += w0.x; a0.y += w0.y; a0.z += w0.z; a0.w += w0.w;
            a1.x += w1.x; a1.y += w1.y; a1.z += w1.z; a1.w += w1.w;
        }
        if (s1 < nloc) {
            float4 w0 = wp[(size_t)e1 * 16];
            float4 w1 = wp[(size_t)e1 * 16 + 1];
            a0.x += w0.x; a0.y += w0.y; a0.z += w0.z; a0.w += w0.w;
            a1.x += w1.x; a1.y += w1.y; a1.z += w1.z; a1.w += w1.w;
        }
    }
    // Rare long-row fallback (deg > 64): plain memory loads, divergence OK
    // (no shuffles inside).
    for (int j = beg + 64 + sub; j < end; j += 8) {
        int e = ids[j];
        float4 w0 = wp[(size_t)e * 16];
        float4 w1 = wp[(size_t)e * 16 + 1];
        a0.x += w0.x; a0.y += w0.y; a0.z += w0.z; a0.w += w0.w;
        a1.x += w1.x; a1.y += w1.y; a1.z += w1.z; a1.w += w1.w;
    }

    #pragma unroll
    for (int m = 8; m < 64; m <<= 1) {
        a0.x += __shfl_xor(a0.x, m); a0.y += __shfl_xor(a0.y, m);
        a0.z += __shfl_xor(a0.z, m); a0.w += __shfl_xor(a0.w, m);
        a1.x += __shfl_xor(a1.x, m); a1.y += __shfl_xor(a1.y, m);
        a1.z += __shfl_xor(a1.z, m); a1.w += __shfl_xor(a1.w, m);
    }
    if (sub == 0) {
        out4[(size_t)row * 16 + g * 2]     = a0;
        out4[(size_t)row * 16 + g * 2 + 1] = a1;
    }
}

extern "C" void kernel_launch(void* const* d_in, const int* in_sizes, int n_in,
                              void* d_out, int out_size, void* d_ws, size_t ws_size,
                              hipStream_t stream) {
    const int*   edge   = (const int*)d_in[0];     // (2,E) int32; rows = edge[0,:]
    const float* edge_w = (const float*)d_in[1];   // (E, 64) float32
    int E = in_sizes[0] / 2;
    int N = out_size / 64;
    int numTiles = (N + TILE - 1) / TILE;          // 49 for N=50000 (must be <=64)

    // Workspace (int32): [counts N][offsets N+1][rank E][ids E][tileSum 64]
    int* counts  = (int*)d_ws;
    int* offsets = counts + N;
    int* rank    = offsets + N + 1;
    int* ids     = rank + E;
    int* tileSum = ids + E;

    (void)hipMemsetAsync(counts, 0, (size_t)N * sizeof(int), stream);

    int blocksE = (E + 1023) / 1024;               // 4 edges per thread
    hist_rank_kernel<<<blocksE, 256, 0, stream>>>(edge, counts, rank, E);
    scan_partial<<<numTiles, 256, 0, stream>>>(counts, tileSum, N);
    scan_final<<<numTiles, 256, 0, stream>>>(counts, tileSum, offsets, N, E, numTiles);
    scatter_kernel<<<blocksE, 256, 0, stream>>>(edge, rank, offsets, ids, E);

    int blocksR = (N + 3) / 4;
    reduce_kernel<<<blocksR, 256, 0, stream>>>(offsets, ids, (const float4*)edge_w,
                                               (float4*)d_out, N);
}